// Round 13
// baseline (18.219 us; speedup 1.0000x reference)
//
#include <hip/hip_runtime.h>

#define FK_NQ 7
#define FK_BLOCK 256
// so[] oversized to pad LDS to ~36.4 KB/block -> exactly 4 blocks/CU
// (160/36.4 = 4.4). 2048 blocks / (256 CU x 4) = TWO generations: gen-2's
// q-loads + compute overlap gen-1's store drain. Single variable vs round 8.
#define SO_PAD 1024

typedef float f32x4 __attribute__((ext_vector_type(4)));

// Per-joint LDS record: 3 float4 at c4[j*3 + {0,1,2}]
//   [0] qj  = quat(R_joint)              (w,x,y,z)
//   [1] qjw = qj (x) (0, w/|w|)          (w,x,y,z)
//   [2] (t_j.x, t_j.y, t_j.z, 0.5*|w|)
// c4[21] = (px, py, pz, 0)  -- link_xyz[idx]
//
// Joint j rotation quaternion: cos(halfn*th)*qj + sin(halfn*th)*qjw
//   == quat(R_joint_j) (x) quat(Rodrigues(w, th))

__device__ __forceinline__ void qmul(const float* a, const float* b, float* r)
{
    r[0] = a[0]*b[0] - a[1]*b[1] - a[2]*b[2] - a[3]*b[3];
    r[1] = a[0]*b[1] + a[1]*b[0] + a[2]*b[3] - a[3]*b[2];
    r[2] = a[0]*b[2] - a[1]*b[3] + a[2]*b[0] + a[3]*b[1];
    r[3] = a[0]*b[3] + a[1]*b[2] - a[2]*b[1] + a[3]*b[0];
}

__global__ __launch_bounds__(FK_BLOCK, 4) void fk_fused(
    const float* __restrict__ q,
    const float* __restrict__ joint_xyz,
    const float* __restrict__ joint_rpy,
    const float* __restrict__ joint_axis,
    const float* __restrict__ link_xyz,
    const int*   __restrict__ idxp,
    float* __restrict__ out,
    unsigned nb)
{
    __shared__ float4 c4[22];
    // Output staging: item i's row r at so[i*5 + r] (stride 5 float4s:
    // bank-spread, 16B aligned -> ~free). Oversized for occupancy control.
    __shared__ f32x4 so[FK_BLOCK * 5 + SO_PAD];

    const int tid = threadIdx.x;
    const unsigned bbase = blockIdx.x * FK_BLOCK;
    const unsigned b = bbase + tid;
    const bool valid = (b < nb);

    // q loads first; HBM latency overlaps the setup + barrier.
    float th[FK_NQ];
    if (valid) {
        const float* qp = q + (size_t)b * FK_NQ;
        #pragma unroll
        for (int j = 0; j < FK_NQ; ++j) th[j] = qp[j];
    }

    // Lanes 0..6: build joint records; lane 7: link offset.
    if (tid < FK_NQ) {
        const int j = tid;
        float rr = joint_rpy[j*3+0], pp = joint_rpy[j*3+1], yy = joint_rpy[j*3+2];
        float sr, cr, sp2, cp2, sy, cy;
        __sincosf(0.5f*rr, &sr, &cr);
        __sincosf(0.5f*pp, &sp2, &cp2);
        __sincosf(0.5f*yy, &sy, &cy);
        float qx[4] = {cr, sr, 0.f, 0.f};
        float qy[4] = {cp2, 0.f, sp2, 0.f};
        float qz[4] = {cy, 0.f, 0.f, sy};
        float tmp[4], qj[4];
        qmul(qy, qx, tmp);
        qmul(qz, tmp, qj);

        float w0 = joint_axis[j*3+0], w1 = joint_axis[j*3+1], w2 = joint_axis[j*3+2];
        float n  = sqrtf(w0*w0 + w1*w1 + w2*w2);
        float ninv = 1.0f/n;
        float qu[4] = {0.f, w0*ninv, w1*ninv, w2*ninv};
        float qjw[4];
        qmul(qj, qu, qjw);

        c4[j*3+0] = make_float4(qj[0],  qj[1],  qj[2],  qj[3]);
        c4[j*3+1] = make_float4(qjw[0], qjw[1], qjw[2], qjw[3]);
        c4[j*3+2] = make_float4(joint_xyz[j*3+0], joint_xyz[j*3+1],
                                joint_xyz[j*3+2], 0.5f*n);
    } else if (tid == FK_NQ) {
        const int ix = idxp[0];
        c4[21] = make_float4(link_xyz[ix*3+0], link_xyz[ix*3+1],
                             link_xyz[ix*3+2], 0.0f);
    }
    __syncthreads();

    if (valid) {
        // j = 0
        float4 j0q = c4[0], j0w = c4[1], j0t = c4[2];
        float sv, cv;
        __sincosf(j0t.w * th[0], &sv, &cv);
        float Qw = cv*j0q.x + sv*j0w.x;
        float Qx = cv*j0q.y + sv*j0w.y;
        float Qy = cv*j0q.z + sv*j0w.z;
        float Qz = cv*j0q.w + sv*j0w.w;
        float tx = j0t.x, ty = j0t.y, tz = j0t.z;

        #pragma unroll
        for (int j = 1; j < FK_NQ; ++j) {
            float4 jq = c4[j*3+0], jw = c4[j*3+1], jt = c4[j*3+2];
            float s, c;
            __sincosf(jt.w * th[j], &s, &c);
            // t += R(Q) * t_j   (v + 2(w*(u×v) + u×(u×v)))
            float vx = jt.x, vy = jt.y, vz = jt.z;
            float c1x = Qy*vz - Qz*vy;
            float c1y = Qz*vx - Qx*vz;
            float c1z = Qx*vy - Qy*vx;
            float c2x = Qw*c1x + (Qy*c1z - Qz*c1y);
            float c2y = Qw*c1y + (Qz*c1x - Qx*c1z);
            float c2z = Qw*c1z + (Qx*c1y - Qy*c1x);
            tx += vx + 2.0f*c2x;
            ty += vy + 2.0f*c2y;
            tz += vz + 2.0f*c2z;
            // qstep = c*qj + s*qjw
            float sw = c*jq.x + s*jw.x;
            float sx = c*jq.y + s*jw.y;
            float sy = c*jq.z + s*jw.z;
            float sz = c*jq.w + s*jw.w;
            // Q = Q (x) qstep
            float nw = Qw*sw - Qx*sx - Qy*sy - Qz*sz;
            float nx = Qw*sx + Qx*sw + Qy*sz - Qz*sy;
            float ny = Qw*sy - Qx*sz + Qy*sw + Qz*sx;
            float nz = Qw*sz + Qx*sy - Qy*sx + Qz*sw;
            Qw = nw; Qx = nx; Qy = ny; Qz = nz;
        }

        // Q -> rotation matrix
        float xx = Qx*Qx, yy = Qy*Qy, zz = Qz*Qz;
        float xy = Qx*Qy, xz = Qx*Qz, yz = Qy*Qz;
        float wx = Qw*Qx, wy = Qw*Qy, wz = Qw*Qz;
        float M00 = 1.0f - 2.0f*(yy+zz);
        float M01 = 2.0f*(xy - wz);
        float M02 = 2.0f*(xz + wy);
        float M10 = 2.0f*(xy + wz);
        float M11 = 1.0f - 2.0f*(xx+zz);
        float M12 = 2.0f*(yz - wx);
        float M20 = 2.0f*(xz - wy);
        float M21 = 2.0f*(yz + wx);
        float M22 = 1.0f - 2.0f*(xx+yy);

        float4 lp = c4[21];
        so[tid*5+0] = (f32x4){M00, M01, M02, M00*lp.x + M01*lp.y + M02*lp.z + tx};
        so[tid*5+1] = (f32x4){M10, M11, M12, M10*lp.x + M11*lp.y + M12*lp.z + ty};
        so[tid*5+2] = (f32x4){M20, M21, M22, M20*lp.x + M21*lp.y + M22*lp.z + tz};
        so[tid*5+3] = (f32x4){0.0f, 0.0f, 0.0f, 1.0f};
    }
    __syncthreads();

    if (bbase + FK_BLOCK <= nb) {
        // Lane-contiguous dwordx4 stores: 16 full 64B lines per instruction.
        f32x4* o = (f32x4*)out + (size_t)bbase * 4u;
        #pragma unroll
        for (int k = 0; k < 4; ++k) {
            unsigned w = k*FK_BLOCK + tid;           // block-local float4 idx
            o[w] = so[(w >> 2)*5 + (w & 3)];
        }
    } else if (valid) {
        // Tail block: per-item stores from this thread's own staging.
        f32x4* o = (f32x4*)(out + (size_t)b * 16u);
        #pragma unroll
        for (int r = 0; r < 4; ++r) o[r] = so[tid*5 + r];
    }
}

extern "C" void kernel_launch(void* const* d_in, const int* in_sizes, int n_in,
                              void* d_out, int out_size, void* d_ws, size_t ws_size,
                              hipStream_t stream) {
    const float* q          = (const float*)d_in[0];
    const float* joint_xyz  = (const float*)d_in[1];
    const float* joint_rpy  = (const float*)d_in[2];
    const float* joint_axis = (const float*)d_in[3];
    const float* link_xyz   = (const float*)d_in[4];
    const int*   idxp       = (const int*)d_in[5];
    float* out = (float*)d_out;

    const unsigned nb = (unsigned)(in_sizes[0] / FK_NQ);
    const int grid = (int)((nb + FK_BLOCK - 1) / FK_BLOCK);

    fk_fused<<<grid, FK_BLOCK, 0, stream>>>(q, joint_xyz, joint_rpy, joint_axis,
                                            link_xyz, idxp, out, nb);
}

// Round 14
// 17.044 us; speedup vs baseline: 1.0689x; 1.0689x over previous
//
#include <hip/hip_runtime.h>

#define FK_NQ 7
#define FK_BLOCK 256

// FINAL: round-8 structure (best measured: 17.2 us).
// Ledger: store-coalescing via LDS transpose was the one real win (-4.6us);
// ILP-2, read-staging, persistent pipeline, nontemporal, generation-split
// all null -> at the traffic + overhead floor (48 MB / 6.5 TB/s ~ 7.4 us GPU
// + replay overhead + read ramp).
//
// Per-joint LDS record: 3 float4 at c4[j*3 + {0,1,2}]
//   [0] qj  = quat(R_joint)              (w,x,y,z)
//   [1] qjw = qj (x) (0, w/|w|)          (w,x,y,z)
//   [2] (t_j.x, t_j.y, t_j.z, 0.5*|w|)
// c4[21] = (px, py, pz, 0)  -- link_xyz[idx]
//
// Joint j rotation quaternion: cos(halfn*th)*qj + sin(halfn*th)*qjw
//   == quat(R_joint_j) (x) quat(Rodrigues(w, th))

__device__ __forceinline__ void qmul(const float* a, const float* b, float* r)
{
    r[0] = a[0]*b[0] - a[1]*b[1] - a[2]*b[2] - a[3]*b[3];
    r[1] = a[0]*b[1] + a[1]*b[0] + a[2]*b[3] - a[3]*b[2];
    r[2] = a[0]*b[2] - a[1]*b[3] + a[2]*b[0] + a[3]*b[1];
    r[3] = a[0]*b[3] + a[1]*b[2] - a[2]*b[1] + a[3]*b[0];
}

__global__ __launch_bounds__(FK_BLOCK, 8) void fk_fused(
    const float* __restrict__ q,
    const float* __restrict__ joint_xyz,
    const float* __restrict__ joint_rpy,
    const float* __restrict__ joint_axis,
    const float* __restrict__ link_xyz,
    const int*   __restrict__ idxp,
    float* __restrict__ out,
    unsigned nb)
{
    __shared__ float4 c4[22];
    // Output staging: item i's row r at so[i*5 + r] (stride 5 float4s:
    // bank-spread, 16B aligned -> ~free).
    __shared__ float4 so[FK_BLOCK * 5];

    const int tid = threadIdx.x;
    const unsigned bbase = blockIdx.x * FK_BLOCK;
    const unsigned b = bbase + tid;
    const bool valid = (b < nb);

    // q loads first: HBM latency overlaps the setup + barrier.
    float th[FK_NQ];
    if (valid) {
        const float* qp = q + (size_t)b * FK_NQ;
        #pragma unroll
        for (int j = 0; j < FK_NQ; ++j) th[j] = qp[j];
    }

    // Lanes 0..6: build joint records; lane 7: link offset.
    if (tid < FK_NQ) {
        const int j = tid;
        float rr = joint_rpy[j*3+0], pp = joint_rpy[j*3+1], yy = joint_rpy[j*3+2];
        float sr, cr, sp2, cp2, sy, cy;
        __sincosf(0.5f*rr, &sr, &cr);
        __sincosf(0.5f*pp, &sp2, &cp2);
        __sincosf(0.5f*yy, &sy, &cy);
        float qx[4] = {cr, sr, 0.f, 0.f};
        float qy[4] = {cp2, 0.f, sp2, 0.f};
        float qz[4] = {cy, 0.f, 0.f, sy};
        float tmp[4], qj[4];
        qmul(qy, qx, tmp);
        qmul(qz, tmp, qj);

        float w0 = joint_axis[j*3+0], w1 = joint_axis[j*3+1], w2 = joint_axis[j*3+2];
        float n  = sqrtf(w0*w0 + w1*w1 + w2*w2);
        float ninv = 1.0f/n;
        float qu[4] = {0.f, w0*ninv, w1*ninv, w2*ninv};
        float qjw[4];
        qmul(qj, qu, qjw);

        c4[j*3+0] = make_float4(qj[0],  qj[1],  qj[2],  qj[3]);
        c4[j*3+1] = make_float4(qjw[0], qjw[1], qjw[2], qjw[3]);
        c4[j*3+2] = make_float4(joint_xyz[j*3+0], joint_xyz[j*3+1],
                                joint_xyz[j*3+2], 0.5f*n);
    } else if (tid == FK_NQ) {
        const int ix = idxp[0];
        c4[21] = make_float4(link_xyz[ix*3+0], link_xyz[ix*3+1],
                             link_xyz[ix*3+2], 0.0f);
    }
    __syncthreads();

    if (valid) {
        // j = 0
        float4 j0q = c4[0], j0w = c4[1], j0t = c4[2];
        float sv, cv;
        __sincosf(j0t.w * th[0], &sv, &cv);
        float Qw = cv*j0q.x + sv*j0w.x;
        float Qx = cv*j0q.y + sv*j0w.y;
        float Qy = cv*j0q.z + sv*j0w.z;
        float Qz = cv*j0q.w + sv*j0w.w;
        float tx = j0t.x, ty = j0t.y, tz = j0t.z;

        #pragma unroll
        for (int j = 1; j < FK_NQ; ++j) {
            float4 jq = c4[j*3+0], jw = c4[j*3+1], jt = c4[j*3+2];
            float s, c;
            __sincosf(jt.w * th[j], &s, &c);
            // t += R(Q) * t_j   (v + 2(w*(u×v) + u×(u×v)))
            float vx = jt.x, vy = jt.y, vz = jt.z;
            float c1x = Qy*vz - Qz*vy;
            float c1y = Qz*vx - Qx*vz;
            float c1z = Qx*vy - Qy*vx;
            float c2x = Qw*c1x + (Qy*c1z - Qz*c1y);
            float c2y = Qw*c1y + (Qz*c1x - Qx*c1z);
            float c2z = Qw*c1z + (Qx*c1y - Qy*c1x);
            tx += vx + 2.0f*c2x;
            ty += vy + 2.0f*c2y;
            tz += vz + 2.0f*c2z;
            // qstep = c*qj + s*qjw
            float sw = c*jq.x + s*jw.x;
            float sx = c*jq.y + s*jw.y;
            float sy = c*jq.z + s*jw.z;
            float sz = c*jq.w + s*jw.w;
            // Q = Q (x) qstep
            float nw = Qw*sw - Qx*sx - Qy*sy - Qz*sz;
            float nx = Qw*sx + Qx*sw + Qy*sz - Qz*sy;
            float ny = Qw*sy - Qx*sz + Qy*sw + Qz*sx;
            float nz = Qw*sz + Qx*sy - Qy*sx + Qz*sw;
            Qw = nw; Qx = nx; Qy = ny; Qz = nz;
        }

        // Q -> rotation matrix
        float xx = Qx*Qx, yy = Qy*Qy, zz = Qz*Qz;
        float xy = Qx*Qy, xz = Qx*Qz, yz = Qy*Qz;
        float wx = Qw*Qx, wy = Qw*Qy, wz = Qw*Qz;
        float M00 = 1.0f - 2.0f*(yy+zz);
        float M01 = 2.0f*(xy - wz);
        float M02 = 2.0f*(xz + wy);
        float M10 = 2.0f*(xy + wz);
        float M11 = 1.0f - 2.0f*(xx+zz);
        float M12 = 2.0f*(yz - wx);
        float M20 = 2.0f*(xz - wy);
        float M21 = 2.0f*(yz + wx);
        float M22 = 1.0f - 2.0f*(xx+yy);

        float4 lp = c4[21];
        so[tid*5+0] = make_float4(M00, M01, M02, M00*lp.x + M01*lp.y + M02*lp.z + tx);
        so[tid*5+1] = make_float4(M10, M11, M12, M10*lp.x + M11*lp.y + M12*lp.z + ty);
        so[tid*5+2] = make_float4(M20, M21, M22, M20*lp.x + M21*lp.y + M22*lp.z + tz);
        so[tid*5+3] = make_float4(0.0f, 0.0f, 0.0f, 1.0f);
    }
    __syncthreads();

    if (bbase + FK_BLOCK <= nb) {
        // Lane-contiguous dwordx4 stores: 16 full 64B lines per instruction.
        float4* o = (float4*)out + (size_t)bbase * 4u;
        #pragma unroll
        for (int k = 0; k < 4; ++k) {
            unsigned w = k*FK_BLOCK + tid;           // block-local float4 idx
            o[w] = so[(w >> 2)*5 + (w & 3)];
        }
    } else if (valid) {
        // Tail block: per-item stores from this thread's own staging.
        float4* o = (float4*)(out + (size_t)b * 16u);
        #pragma unroll
        for (int r = 0; r < 4; ++r) o[r] = so[tid*5 + r];
    }
}

extern "C" void kernel_launch(void* const* d_in, const int* in_sizes, int n_in,
                              void* d_out, int out_size, void* d_ws, size_t ws_size,
                              hipStream_t stream) {
    const float* q          = (const float*)d_in[0];
    const float* joint_xyz  = (const float*)d_in[1];
    const float* joint_rpy  = (const float*)d_in[2];
    const float* joint_axis = (const float*)d_in[3];
    const float* link_xyz   = (const float*)d_in[4];
    const int*   idxp       = (const int*)d_in[5];
    float* out = (float*)d_out;

    const unsigned nb = (unsigned)(in_sizes[0] / FK_NQ);
    const int grid = (int)((nb + FK_BLOCK - 1) / FK_BLOCK);

    fk_fused<<<grid, FK_BLOCK, 0, stream>>>(q, joint_xyz, joint_rpy, joint_axis,
                                            link_xyz, idxp, out, nb);
}